// Round 4
// baseline (343.868 us; speedup 1.0000x reference)
//
#include <hip/hip_runtime.h>

#define TT 2048
#define BB 8192
#define NCHUNK 32
#define SS 64              // outputs per chunk
#define WW 64              // warmup steps (decay ~e^-35 typical; absmax floor is arithmetic, not truncation)

struct SC {
  float axs[4], bs[4], u0s[4], u1s[4];          // r,z gates, prescaled by -log2(e)
  float axn[2], bxn[2], an0[2], an1[2], bhn[2]; // n gate, prescaled by 2*log2(e)
};

// Force a wave-uniform float into an SGPR (constants live in SGPRs, not VGPRs).
__device__ __forceinline__ float rfl(float x) {
  return __int_as_float(__builtin_amdgcn_readfirstlane(__float_as_int(x)));
}
__device__ __forceinline__ float rcpf_(float v)  { return __builtin_amdgcn_rcpf(v); }
__device__ __forceinline__ float exp2f_(float v) { return __builtin_amdgcn_exp2f(v); }

// One GRU step: sigmoid(u) = rcp(1+exp2(u_scaled)), tanh(v) = 1-2*rcp(1+exp2(v_scaled)).
__device__ __forceinline__ void gru_step(const SC& K, float xs, float& h0, float& h1)
{
  float u0 = fmaf(K.u1s[0], h1, fmaf(K.u0s[0], h0, fmaf(K.axs[0], xs, K.bs[0])));
  float u1 = fmaf(K.u1s[1], h1, fmaf(K.u0s[1], h0, fmaf(K.axs[1], xs, K.bs[1])));
  float u2 = fmaf(K.u1s[2], h1, fmaf(K.u0s[2], h0, fmaf(K.axs[2], xs, K.bs[2])));
  float u3 = fmaf(K.u1s[3], h1, fmaf(K.u0s[3], h0, fmaf(K.axs[3], xs, K.bs[3])));
  float r0 = rcpf_(1.f + exp2f_(u0));
  float r1 = rcpf_(1.f + exp2f_(u1));
  float z0 = rcpf_(1.f + exp2f_(u2));
  float z1 = rcpf_(1.f + exp2f_(u3));
  float gxn0 = fmaf(K.axn[0], xs, K.bxn[0]);
  float gxn1 = fmaf(K.axn[1], xs, K.bxn[1]);
  float ghn0 = fmaf(K.an1[0], h1, fmaf(K.an0[0], h0, K.bhn[0]));
  float ghn1 = fmaf(K.an1[1], h1, fmaf(K.an0[1], h0, K.bhn[1]));
  float n0 = fmaf(-2.f, rcpf_(1.f + exp2f_(fmaf(r0, ghn0, gxn0))), 1.f);
  float n1 = fmaf(-2.f, rcpf_(1.f + exp2f_(fmaf(r1, ghn1, gxn1))), 1.f);
  h0 = fmaf(z0, h0 - n0, n0);   // (1-z)*n + z*h
  h1 = fmaf(z1, h1 - n1, n1);
}

// exp(t), |t|<=1: Taylor deg 7, |err| < 3e-5
__device__ __forceinline__ float exp_t(float t) {
  float e = fmaf(t, 1.9841270e-4f, 1.3888889e-3f);
  e = fmaf(t, e, 8.3333333e-3f);
  e = fmaf(t, e, 4.1666667e-2f);
  e = fmaf(t, e, 0.16666667f);
  e = fmaf(t, e, 0.5f);
  e = fmaf(t, e, 1.f);
  e = fmaf(t, e, 1.f);
  return e;
}

// |h|<1 always (convex combination of tanh outputs). tanh via Pade(5,4):
// tanh(x)=x(945+105x^2+x^4)/(945+420x^2+15x^4), err<1e-7 on [-1,1].
__device__ __forceinline__ float pade_tanh(float x) {
  float w = x * x;
  float num = x * fmaf(w, fmaf(w, 1.f, 105.f), 945.f);
  float den = fmaf(w, fmaf(w, 15.f, 420.f), 945.f);
  return num * rcpf_(den);
}

__device__ __forceinline__ float2 epilogue(float h0, float h1)
{
  float t0 = pade_tanh(h0);
  float t1 = pade_tanh(h1);
  float alpha = 2.5f * exp_t(t0);                 // 2.5*exp(t0), no trans
  // 4*sigmoid(t1) = 2 + 2*tanh(t1/2); |t1/2|<=0.5 -> Pade err ~1e-9
  float beta = fmaf(2.f, pade_tanh(0.5f * t1), 2.f);
  return make_float2(alpha, beta);
}

__global__ __launch_bounds__(256)
void WTTERNN_gru(const float* __restrict__ xg, const float* __restrict__ wih,
                 const float* __restrict__ whh, const float* __restrict__ bih,
                 const float* __restrict__ bhh, float* __restrict__ out)
{
  const float L1 = -1.4426950408889634f;
  const float L2 =  2.8853900817779268f;
  SC K;
  #pragma unroll
  for (int g = 0; g < 4; ++g) {
    K.axs[g] = rfl(L1 * wih[g]);
    K.bs [g] = rfl(L1 * (bih[g] + bhh[g]));
    K.u0s[g] = rfl(L1 * whh[2*g]);
    K.u1s[g] = rfl(L1 * whh[2*g + 1]);
  }
  #pragma unroll
  for (int j = 0; j < 2; ++j) {
    K.axn[j] = rfl(L2 * wih[4+j]);
    K.bxn[j] = rfl(L2 * bih[4+j]);
    K.an0[j] = rfl(L2 * whh[2*(4+j)]);
    K.an1[j] = rfl(L2 * whh[2*(4+j) + 1]);
    K.bhn[j] = rfl(L2 * bhh[4+j]);
  }

  // 131072 threads: thread (b, g) runs chunks g and g+16 of row b (2-chain ILP).
  const int tid = blockIdx.x * blockDim.x + threadIdx.x;
  const int b = tid & (BB - 1);
  const int g = tid >> 13;             // 0..15, block-uniform
  const float* xp = xg + (size_t)b * TT;
  float4* out4 = (float4*)out;
  const size_t obase = ((size_t)b * TT) >> 1; // float4 index of row start

  const int toutA = g * SS;            // 0..960
  const int toutB = (g + 16) * SS;     // 1024..1984

  float hA0 = 0.f, hA1 = 0.f, hB0 = 0.f, hB1 = 0.f;

  float4 xb = *reinterpret_cast<const float4*>(xp + (toutB - WW));
  float4 xa;

  if (g != 0) {
    // Warmup both chains.
    xa = *reinterpret_cast<const float4*>(xp + (toutA - WW));
    const int baseA = toutA - WW, baseB = toutB - WW;
    for (int i = 0; i < WW; i += 4) {
      const float4 na = *reinterpret_cast<const float4*>(xp + baseA + i + 4);
      const float4 nb = *reinterpret_cast<const float4*>(xp + baseB + i + 4);
      gru_step(K, xa.x, hA0, hA1); gru_step(K, xb.x, hB0, hB1);
      gru_step(K, xa.y, hA0, hA1); gru_step(K, xb.y, hB0, hB1);
      gru_step(K, xa.z, hA0, hA1); gru_step(K, xb.z, hB0, hB1);
      gru_step(K, xa.w, hA0, hA1); gru_step(K, xb.w, hB0, hB1);
      xa = na; xb = nb;
    }
  } else {
    // Chunk 0 starts exactly at h=0 (true initial state): warmup B only.
    const int baseB = toutB - WW;
    for (int i = 0; i < WW; i += 4) {
      const float4 nb = *reinterpret_cast<const float4*>(xp + baseB + i + 4);
      gru_step(K, xb.x, hB0, hB1);
      gru_step(K, xb.y, hB0, hB1);
      gru_step(K, xb.z, hB0, hB1);
      gru_step(K, xb.w, hB0, hB1);
      xb = nb;
    }
    xa = *reinterpret_cast<const float4*>(xp + 0);
  }

  // Output phase: both chains emit SS outputs.
  for (int i = 0; i < SS; i += 4) {
    int inA = toutA + i + 4; if (inA + 4 > TT) inA = toutA + i;   // clamp dummy
    int inB = toutB + i + 4; if (inB + 4 > TT) inB = toutB + i;
    const float4 na = *reinterpret_cast<const float4*>(xp + inA);
    const float4 nb = *reinterpret_cast<const float4*>(xp + inB);

    gru_step(K, xa.x, hA0, hA1); float2 a0 = epilogue(hA0, hA1);
    gru_step(K, xb.x, hB0, hB1); float2 b0 = epilogue(hB0, hB1);
    gru_step(K, xa.y, hA0, hA1); float2 a1 = epilogue(hA0, hA1);
    gru_step(K, xb.y, hB0, hB1); float2 b1 = epilogue(hB0, hB1);
    out4[obase + (size_t)((toutA + i) >> 1)]     = make_float4(a0.x, a0.y, a1.x, a1.y);
    out4[obase + (size_t)((toutB + i) >> 1)]     = make_float4(b0.x, b0.y, b1.x, b1.y);
    gru_step(K, xa.z, hA0, hA1); float2 a2 = epilogue(hA0, hA1);
    gru_step(K, xb.z, hB0, hB1); float2 b2 = epilogue(hB0, hB1);
    gru_step(K, xa.w, hA0, hA1); float2 a3 = epilogue(hA0, hA1);
    gru_step(K, xb.w, hB0, hB1); float2 b3 = epilogue(hB0, hB1);
    out4[obase + (size_t)((toutA + i) >> 1) + 1] = make_float4(a2.x, a2.y, a3.x, a3.y);
    out4[obase + (size_t)((toutB + i) >> 1) + 1] = make_float4(b2.x, b2.y, b3.x, b3.y);
    xa = na; xb = nb;
  }
}

extern "C" void kernel_launch(void* const* d_in, const int* in_sizes, int n_in,
                              void* d_out, int out_size, void* d_ws, size_t ws_size,
                              hipStream_t stream)
{
  (void)in_sizes; (void)n_in; (void)out_size; (void)d_ws; (void)ws_size;
  const float* x   = (const float*)d_in[0];
  const float* wih = (const float*)d_in[1];
  const float* whh = (const float*)d_in[2];
  const float* bih = (const float*)d_in[3];
  const float* bhh = (const float*)d_in[4];
  float* out = (float*)d_out;

  dim3 grid((BB * NCHUNK / 2) / 256);   // 131072 threads, 2 chains each
  dim3 block(256);
  hipLaunchKernelGGL(WTTERNN_gru, grid, block, 0, stream, x, wih, whh, bih, bhh, out);
}

// Round 5
// 265.485 us; speedup vs baseline: 1.2952x; 1.2952x over previous
//
#include <hip/hip_runtime.h>

#define TT 2048
#define BB 8192
#define SS 64              // outputs per chunk (32 chunks)
#define WW 64              // warmup steps
#define TILE_T 16          // t-steps per LDS tile

struct SC {
  float axs[4], bs[4], u0s[4], u1s[4];          // r,z gates, prescaled by -log2(e)
  float axn[2], bxn[2], an0[2], an1[2], bhn[2]; // n gate, prescaled by 2*log2(e)
};

// Force a wave-uniform float into an SGPR.
__device__ __forceinline__ float rfl(float x) {
  return __int_as_float(__builtin_amdgcn_readfirstlane(__float_as_int(x)));
}
__device__ __forceinline__ float rcpf_(float v)  { return __builtin_amdgcn_rcpf(v); }
__device__ __forceinline__ float exp2f_(float v) { return __builtin_amdgcn_exp2f(v); }

// sigmoid(u) = rcp(1+exp2(u_scaled)), tanh(v) = 1-2*rcp(1+exp2(v_scaled)).
__device__ __forceinline__ void gru_step(const SC& K, float xs, float& h0, float& h1)
{
  float u0 = fmaf(K.u1s[0], h1, fmaf(K.u0s[0], h0, fmaf(K.axs[0], xs, K.bs[0])));
  float u1 = fmaf(K.u1s[1], h1, fmaf(K.u0s[1], h0, fmaf(K.axs[1], xs, K.bs[1])));
  float u2 = fmaf(K.u1s[2], h1, fmaf(K.u0s[2], h0, fmaf(K.axs[2], xs, K.bs[2])));
  float u3 = fmaf(K.u1s[3], h1, fmaf(K.u0s[3], h0, fmaf(K.axs[3], xs, K.bs[3])));
  float r0 = rcpf_(1.f + exp2f_(u0));
  float r1 = rcpf_(1.f + exp2f_(u1));
  float z0 = rcpf_(1.f + exp2f_(u2));
  float z1 = rcpf_(1.f + exp2f_(u3));
  float gxn0 = fmaf(K.axn[0], xs, K.bxn[0]);
  float gxn1 = fmaf(K.axn[1], xs, K.bxn[1]);
  float ghn0 = fmaf(K.an1[0], h1, fmaf(K.an0[0], h0, K.bhn[0]));
  float ghn1 = fmaf(K.an1[1], h1, fmaf(K.an0[1], h0, K.bhn[1]));
  float n0 = fmaf(-2.f, rcpf_(1.f + exp2f_(fmaf(r0, ghn0, gxn0))), 1.f);
  float n1 = fmaf(-2.f, rcpf_(1.f + exp2f_(fmaf(r1, ghn1, gxn1))), 1.f);
  h0 = fmaf(z0, h0 - n0, n0);   // (1-z)*n + z*h
  h1 = fmaf(z1, h1 - n1, n1);
}

// exp(t), |t|<=1: Taylor deg 7, |err| < 3e-5
__device__ __forceinline__ float exp_t(float t) {
  float e = fmaf(t, 1.9841270e-4f, 1.3888889e-3f);
  e = fmaf(t, e, 8.3333333e-3f);
  e = fmaf(t, e, 4.1666667e-2f);
  e = fmaf(t, e, 0.16666667f);
  e = fmaf(t, e, 0.5f);
  e = fmaf(t, e, 1.f);
  e = fmaf(t, e, 1.f);
  return e;
}

// |h|<1 (convex combination of tanh outputs). Pade(5,4) tanh, err<1e-7 on [-1,1].
__device__ __forceinline__ float pade_tanh(float x) {
  float w = x * x;
  float num = x * fmaf(w, fmaf(w, 1.f, 105.f), 945.f);
  float den = fmaf(w, fmaf(w, 15.f, 420.f), 945.f);
  return num * rcpf_(den);
}

__device__ __forceinline__ float2 epilogue(float h0, float h1)
{
  float t0 = pade_tanh(h0);
  float t1 = pade_tanh(h1);
  float alpha = 2.5f * exp_t(t0);
  float beta  = fmaf(2.f, pade_tanh(0.5f * t1), 2.f);  // 4*sigmoid(t1)
  return make_float2(alpha, beta);
}

__device__ __forceinline__ void quad_out(const SC& K, float4 xv, float& h0, float& h1,
                                         float4* __restrict__ out4, size_t ob, int tg)
{
  gru_step(K, xv.x, h0, h1); float2 e0 = epilogue(h0, h1);
  gru_step(K, xv.y, h0, h1); float2 e1 = epilogue(h0, h1);
  out4[ob + (size_t)(tg >> 1)] = make_float4(e0.x, e0.y, e1.x, e1.y);
  gru_step(K, xv.z, h0, h1); float2 e2 = epilogue(h0, h1);
  gru_step(K, xv.w, h0, h1); float2 e3 = epilogue(h0, h1);
  out4[ob + (size_t)(tg >> 1) + 1] = make_float4(e2.x, e2.y, e3.x, e3.y);
}

__global__ __launch_bounds__(256)
void WTTERNN_gru(const float* __restrict__ xg, const float* __restrict__ wih,
                 const float* __restrict__ whh, const float* __restrict__ bih,
                 const float* __restrict__ bhh, float* __restrict__ out)
{
  // Double-buffered staging tile: [buf][row][t]  (2 x 16 KB)
  __shared__ float lds[2][256][TILE_T];

  const float L1 = -1.4426950408889634f;
  const float L2 =  2.8853900817779268f;
  SC K;
  #pragma unroll
  for (int g = 0; g < 4; ++g) {
    K.axs[g] = rfl(L1 * wih[g]);
    K.bs [g] = rfl(L1 * (bih[g] + bhh[g]));
    K.u0s[g] = rfl(L1 * whh[2*g]);
    K.u1s[g] = rfl(L1 * whh[2*g + 1]);
  }
  #pragma unroll
  for (int j = 0; j < 2; ++j) {
    K.axn[j] = rfl(L2 * wih[4+j]);
    K.bxn[j] = rfl(L2 * bih[4+j]);
    K.an0[j] = rfl(L2 * whh[2*(4+j)]);
    K.an1[j] = rfl(L2 * whh[2*(4+j) + 1]);
    K.bhn[j] = rfl(L2 * bhh[4+j]);
  }

  // Block = 256 consecutive rows x ONE chunk (c block-uniform).
  const int c   = blockIdx.x >> 5;            // chunk 0..31
  const int rb  = (blockIdx.x & 31) << 8;     // row base
  const int row = threadIdx.x;
  const int b   = rb + row;

  const int t0         = c * SS;
  const int tload0     = (c == 0) ? 0 : (t0 - WW);
  const int ntiles     = (c == 0) ? (SS / TILE_T) : ((SS + WW) / TILE_T); // 4 or 8
  const int warm_tiles = (c == 0) ? 0 : (WW / TILE_T);                    // 0 or 4

  // Staging: thread covers rows {srow, srow+64, srow+128, srow+192} at 16B seg stoff.
  // 4 lanes per row -> every fetched 64B line fully consumed by the wave-load.
  const int srow  = threadIdx.x >> 2;
  const int stoff = (threadIdx.x & 3) << 2;   // float offset 0/4/8/12

  float4 stage[4];
  auto gload = [&](int tile) {
    const int tbase = tload0 + tile * TILE_T + stoff;
    #pragma unroll
    for (int p = 0; p < 4; ++p)
      stage[p] = *reinterpret_cast<const float4*>(
          xg + (size_t)(rb + srow + (p << 6)) * TT + tbase);
  };
  auto dswrite = [&](int buf) {
    #pragma unroll
    for (int p = 0; p < 4; ++p)
      *reinterpret_cast<float4*>(&lds[buf][srow + (p << 6)][stoff]) = stage[p];
  };

  float4* out4 = (float4*)out;
  const size_t ob = (size_t)b * 1024;   // float4 units: row stride = 2048*2 floats

  gload(0);
  dswrite(0);
  gload(1);          // ntiles >= 4 always
  __syncthreads();

  float h0 = 0.f, h1 = 0.f;

  for (int i = 0; i < ntiles; ++i) {
    const int buf = i & 1;
    // Pull this thread's 16 x-values to registers (b128 reads, 2-way alias = free).
    float4 xq0 = *reinterpret_cast<const float4*>(&lds[buf][row][0]);
    float4 xq1 = *reinterpret_cast<const float4*>(&lds[buf][row][4]);
    float4 xq2 = *reinterpret_cast<const float4*>(&lds[buf][row][8]);
    float4 xq3 = *reinterpret_cast<const float4*>(&lds[buf][row][12]);

    if (i < warm_tiles) {
      gru_step(K, xq0.x, h0, h1); gru_step(K, xq0.y, h0, h1);
      gru_step(K, xq0.z, h0, h1); gru_step(K, xq0.w, h0, h1);
      gru_step(K, xq1.x, h0, h1); gru_step(K, xq1.y, h0, h1);
      gru_step(K, xq1.z, h0, h1); gru_step(K, xq1.w, h0, h1);
      gru_step(K, xq2.x, h0, h1); gru_step(K, xq2.y, h0, h1);
      gru_step(K, xq2.z, h0, h1); gru_step(K, xq2.w, h0, h1);
      gru_step(K, xq3.x, h0, h1); gru_step(K, xq3.y, h0, h1);
      gru_step(K, xq3.z, h0, h1); gru_step(K, xq3.w, h0, h1);
    } else {
      const int tg = tload0 + i * TILE_T;   // global t of this tile's first step
      quad_out(K, xq0, h0, h1, out4, ob, tg + 0);
      quad_out(K, xq1, h0, h1, out4, ob, tg + 4);
      quad_out(K, xq2, h0, h1, out4, ob, tg + 8);
      quad_out(K, xq3, h0, h1, out4, ob, tg + 12);
    }

    if (i + 1 < ntiles) {
      dswrite(buf ^ 1);                 // buf^1 fully drained (sync at end of prev iter)
      if (i + 2 < ntiles) gload(i + 2); // next-next tile: in flight under compute
      __syncthreads();
    }
  }
}

extern "C" void kernel_launch(void* const* d_in, const int* in_sizes, int n_in,
                              void* d_out, int out_size, void* d_ws, size_t ws_size,
                              hipStream_t stream)
{
  (void)in_sizes; (void)n_in; (void)out_size; (void)d_ws; (void)ws_size;
  const float* x   = (const float*)d_in[0];
  const float* wih = (const float*)d_in[1];
  const float* whh = (const float*)d_in[2];
  const float* bih = (const float*)d_in[3];
  const float* bhh = (const float*)d_in[4];
  float* out = (float*)d_out;

  dim3 grid(32 * 32);    // 32 chunks x 32 row-blocks, 256 rows per block
  dim3 block(256);
  hipLaunchKernelGGL(WTTERNN_gru, grid, block, 0, stream, x, wih, whh, bih, bhh, out);
}